// Round 7
// baseline (3310.471 us; speedup 1.0000x reference)
//
#include <hip/hip_runtime.h>
#include <math.h>

// LSTM B=256, T=2048, D=H=64, OUT=8, fp32.
// Round-13 = round-12 (single-wave recurrence, register-only h-broadcast)
// with the producer x-path hardened: x-row offset pinned to a VGPR so the
// loads are global_load_dwordx4 (vmcnt-tracked, broadcast same-address)
// instead of inviting 100+ SGPRs of s_load chains -- the only untested
// codegen risk in r12 (its "container failed twice" is otherwise
// unattributable: no spin-waits, uniform barriers, bounded loops; infra
// showed 539-1533 s pushes on every round, so flake is the lead theory).
//
// Design (from r6-r11 post-mortems):
//  - 4-wave k-split floor = exchange segment (P-write drain + barrier +
//    P-read ~450 cy/step): r10 (readlane h) and r11 (reg-x, light barrier)
//    both pinned at ~990 us -> attack the exchange itself.
//  - r8/9 single-wave failure was 16 SERIALIZED ds_read_b128 h-reads
//    (~1900 cy/step), not issue limits -> keep single-wave, move the
//    h-broadcast into registers: consumer computes ALL 64 units, so h[k]
//    lives in lane k of the consumer; next step's h-vector = 64 v_readlane
//    (dep only on hj, ~130 cy, no memory, no waits, no barriers).
//  - x-path: TWO producer waves compute xg = scaled(W_ih x_t + b) into a
//    double-buffered LDS ring (8 steps each per 16-step chunk, ~2.6x
//    headroom); sync = r8's proven uniform __syncthreads per chunk.
//  - Registers: gates i,f,g in VGPR (192) + gate o in AGPR (64) = the
//    r9-proven spill-free split. WRITE_SIZE is the spill sentinel.

#define Hh 64
#define Tt 2048
#define Bb 256
#define OUTN 8
#define CH 16                 // steps per chunk (barrier granularity)
#define NCH (Tt / CH)         // 128

typedef float floatx4 __attribute__((ext_vector_type(4)));
typedef float floatx2 __attribute__((ext_vector_type(2)));

__device__ __forceinline__ float hsum4(floatx4 a) {
    floatx2 t = a.lo + a.hi;          // v_pk_add_f32
    return t.x + t.y;
}

// sigma(z) given the PRE-SCALED logit zp = -log2e * z
__device__ __forceinline__ float sigm2(float zp) {
    return __builtin_amdgcn_rcpf(1.0f + __builtin_amdgcn_exp2f(zp));
}

__global__ __launch_bounds__(192, 1)
void lstm_rl_kernel(const float* __restrict__ x,
                    const float* __restrict__ w_ih,
                    const float* __restrict__ w_hh,
                    const float* __restrict__ b_ih,
                    const float* __restrict__ b_hh,
                    const float* __restrict__ fc_w,
                    const float* __restrict__ fc_b,
                    float* __restrict__ out)
{
    __shared__ __align__(16) float ring[2][CH][Hh][4];   // 32 KB xg dbl-buffer

    const int tid  = threadIdx.x;
    const int b    = blockIdx.x;
    const int wave = tid >> 6;     // 0 = consumer, 1/2 = producers
    const int lane = tid & 63;     // hidden unit j

    const float* xb = x + (size_t)b * Tt * Hh;

    const float SC1 = -1.44269504088896340736f;   // -log2(e)
    const float SC2 = -2.88539008177792681472f;   // -2*log2(e)

    // ---- per-wave weights: consumer=W_hh, producers=W_ih (pre-scaled) ----
    // lane j, gate g -> row 64g+j, full 64 cols. Gates i,f,g in VGPR (192),
    // gate o in AGPR (64): the round-9-proven split, spill-free.
    floatx4 wv[3][16];
    floatx4 wa[16];
    {
        const float* wp = (wave == 0) ? w_hh : w_ih;
        #pragma unroll
        for (int g = 0; g < 3; ++g) {
            const float sc = (g == 2) ? SC2 : SC1;
            const floatx4* p = (const floatx4*)(wp + (size_t)((g << 6) + lane) * Hh);
            #pragma unroll
            for (int q = 0; q < 16; ++q) wv[g][q] = p[q] * sc;
        }
        const floatx4* p3 = (const floatx4*)(wp + (size_t)(192 + lane) * Hh);
        #pragma unroll
        for (int q = 0; q < 16; ++q) wa[q] = p3[q] * SC1;

        #pragma unroll
        for (int g = 0; g < 3; ++g)
            #pragma unroll
            for (int q = 0; q < 16; ++q)
                asm volatile("" : "+v"(wv[g][q]));
        #pragma unroll
        for (int q = 0; q < 16; ++q)
            asm volatile("" : "+a"(wa[q]));      // pin o-gate in AGPRs
    }
    floatx4 bias4;                               // used by producers only
    bias4.x = (b_ih[lane]       + b_hh[lane])       * SC1;   // i
    bias4.y = (b_ih[64 + lane]  + b_hh[64 + lane])  * SC1;   // f
    bias4.z = (b_ih[128 + lane] + b_hh[128 + lane]) * SC2;   // g (tanh)
    bias4.w = (b_ih[192 + lane] + b_hh[192 + lane]) * SC1;   // o

    const int sub = wave - 1;     // producer sub-index 0/1

    // producer: fill its 8 steps of the chunk starting at timestep t0.
    // x-row offset pinned to a VGPR -> global_load_dwordx4 path (vmcnt-
    // tracked; all lanes same address -> broadcast-friendly), NOT s_load
    // chains (SGPR pressure risk).
    auto produce = [&](int buf, int t0) {
        #pragma unroll 2
        for (int s8 = 0; s8 < 8; ++s8) {
            const int s = (sub << 3) + s8;
            unsigned voff = (unsigned)((t0 + s) * (Hh * 4));
            asm volatile("" : "+v"(voff));       // force VGPR addressing
            const floatx4* x4 = (const floatx4*)((const char*)xb + voff);
            floatx4 a0, a1, a2, a3;
            {
                floatx4 v = x4[0];
                a0 = wv[0][0] * v; a1 = wv[1][0] * v;
                a2 = wv[2][0] * v; a3 = wa[0] * v;
            }
            #pragma unroll
            for (int q = 1; q < 16; ++q) {
                floatx4 v = x4[q];
                a0 = __builtin_elementwise_fma(wv[0][q], v, a0);
                a1 = __builtin_elementwise_fma(wv[1][q], v, a1);
                a2 = __builtin_elementwise_fma(wv[2][q], v, a2);
                a3 = __builtin_elementwise_fma(wa[q],    v, a3);
            }
            floatx4 xg;
            xg.x = hsum4(a0); xg.y = hsum4(a1);
            xg.z = hsum4(a2); xg.w = hsum4(a3);
            xg += bias4;
            *(floatx4*)&ring[buf][s][lane][0] = xg;
        }
    };

    float c = 0.0f, hj = 0.0f;    // consumer state: c[j], h[j] for j = lane

    if (wave) produce(0, 0);      // chunk 0 ready before first barrier

    for (int cc = 0; cc < NCH; ++cc) {
        __syncthreads();   // ring[cc&1] complete; ring[(cc+1)&1] free

        if (wave) {
            if (cc + 1 < NCH) produce((cc + 1) & 1, (cc + 1) * CH);
        } else {
            #pragma unroll 1
            for (int s = 0; s < CH; ++s) {
                // xg: 1 ds_read_b128, issued first; latency hides under FMAs
                floatx4 xg = *(const floatx4*)&ring[cc & 1][s][lane][0];

                // h-broadcast: pure readlane (h[k] lives in lane k of THIS
                // wave). No LDS, no waits, no barrier.
                const int hb = __float_as_int(hj);
                floatx4 a0, a1, a2, a3;
                {
                    floatx4 hq;
                    hq.x = __int_as_float(__builtin_amdgcn_readlane(hb, 0));
                    hq.y = __int_as_float(__builtin_amdgcn_readlane(hb, 1));
                    hq.z = __int_as_float(__builtin_amdgcn_readlane(hb, 2));
                    hq.w = __int_as_float(__builtin_amdgcn_readlane(hb, 3));
                    a0 = wv[0][0] * hq; a1 = wv[1][0] * hq;
                    a2 = wv[2][0] * hq; a3 = wa[0] * hq;
                }
                #pragma unroll
                for (int q = 1; q < 16; ++q) {
                    floatx4 hq;
                    hq.x = __int_as_float(__builtin_amdgcn_readlane(hb, 4 * q));
                    hq.y = __int_as_float(__builtin_amdgcn_readlane(hb, 4 * q + 1));
                    hq.z = __int_as_float(__builtin_amdgcn_readlane(hb, 4 * q + 2));
                    hq.w = __int_as_float(__builtin_amdgcn_readlane(hb, 4 * q + 3));
                    a0 = __builtin_elementwise_fma(wv[0][q], hq, a0);
                    a1 = __builtin_elementwise_fma(wv[1][q], hq, a1);
                    a2 = __builtin_elementwise_fma(wv[2][q], hq, a2);
                    a3 = __builtin_elementwise_fma(wa[q],    hq, a3);
                }
                floatx4 z;
                z.x = hsum4(a0); z.y = hsum4(a1);
                z.z = hsum4(a2); z.w = hsum4(a3);
                z += xg;                               // bias folded into xg

                float i_ = sigm2(z.x);
                float f_ = sigm2(z.y);
                float g_ = 2.0f * sigm2(z.z) - 1.0f;   // tanh via 2*sigma-1
                float o_ = sigm2(z.w);
                c = __builtin_fmaf(f_, c, i_ * g_);
                float th = 2.0f * sigm2(SC2 * c) - 1.0f;
                hj = o_ * th;                          // stays in-register
            }
        }
    }

    // ---- epilogue: out[b] = h_T @ fc_w^T + fc_b, h via readlane ----
    if (wave == 0 && lane < OUTN) {
        const int hb = __float_as_int(hj);
        float acc = fc_b[lane];
        #pragma unroll
        for (int j = 0; j < Hh; ++j)
            acc = __builtin_fmaf(
                fc_w[lane * Hh + j],
                __int_as_float(__builtin_amdgcn_readlane(hb, j)), acc);
        out[b * OUTN + lane] = acc;
    }
}

extern "C" void kernel_launch(void* const* d_in, const int* in_sizes, int n_in,
                              void* d_out, int out_size, void* d_ws, size_t ws_size,
                              hipStream_t stream) {
    const float* x    = (const float*)d_in[0];
    const float* w_ih = (const float*)d_in[1];
    const float* w_hh = (const float*)d_in[2];
    const float* b_ih = (const float*)d_in[3];
    const float* b_hh = (const float*)d_in[4];
    const float* fc_w = (const float*)d_in[5];
    const float* fc_b = (const float*)d_in[6];
    float* out = (float*)d_out;

    lstm_rl_kernel<<<Bb, 192, 0, stream>>>(x, w_ih, w_hh, b_ih, b_hh,
                                           fc_w, fc_b, out);
}